// Round 1
// baseline (140.504 us; speedup 1.0000x reference)
//
#include <hip/hip_runtime.h>

// Problem: B=8, N=4096, H=256, F=6
//   W_b[h,k] = sum_f osc[f,h,k] * sin(freq_f * t[b] + phase[f,k])
//   out[b,n,k] = sum_h x[b,n,h] * W_b[h,k]
//
// Kernel 1: build W (fp32) into d_ws  [8][256][256]
// Kernel 2: per-batch tiled GEMM, BM=128 BN=64 BK=16, TM=8 TN=4, 256 thr/block

#define B_  8
#define N_  4096
#define H_  256

__global__ __launch_bounds__(256) void build_w(
    const float* __restrict__ osc,     // [6][256][256]
    const float* __restrict__ t,       // [8][1]
    const float* __restrict__ phase,   // [6][256]
    float* __restrict__ W)             // [8][256][256]
{
    const float freqs[6] = {1.f, 2.f, 4.f, 8.f, 7.f, 5.f};
    int idx = blockIdx.x * 256 + threadIdx.x;   // grid = 2048*256 = 8*256*256 exactly
    int b   = idx >> 16;                        // / 65536
    int hn  = idx & 65535;                      // h*256 + n
    int n   = hn & 255;
    float tb = t[b];
    float acc = 0.f;
#pragma unroll
    for (int f = 0; f < 6; ++f) {
        float s = sinf(freqs[f] * tb + phase[f * 256 + n]);
        acc += osc[f * 65536 + hn] * s;
    }
    W[idx] = acc;
}

#define BM 128
#define BN 64
#define BK 16
#define TM 8
#define TN 4
// thread grid: 16 (ty) x 16 (tx) = 256

__global__ __launch_bounds__(256) void gemm(
    const float* __restrict__ X,   // [8][4096][256]
    const float* __restrict__ W,   // [8][256][256]
    float* __restrict__ out)       // [8][4096][256]
{
    __shared__ float As[BK][BM + 4];  // transposed A tile: As[k][m]; +4 pad breaks 4-way write conflict
    __shared__ float Bs[BK][BN];      // Bs[k][n]

    const int b     = blockIdx.z;
    const int mTile = blockIdx.y;     // 0..31
    const int nTile = blockIdx.x;     // 0..3

    const float* Xb = X   + (size_t)b * N_ * H_ + (size_t)mTile * BM * H_;
    const float* Wb = W   + (size_t)b * H_ * H_ + nTile * BN;
    float*       Ob = out + (size_t)b * N_ * H_ + (size_t)mTile * BM * H_ + nTile * BN;

    const int tid = threadIdx.x;
    const int tx  = tid & 15;   // 0..15 -> col group (TN=4)
    const int ty  = tid >> 4;   // 0..15 -> row group (TM=8)

    float c[TM][TN] __attribute__((aligned(16))) = {};

    for (int k0 = 0; k0 < H_; k0 += BK) {
        // ---- stage A: 128 rows x 16 k, 512 float4 loads, 2 per thread, store transposed
#pragma unroll
        for (int i = 0; i < 2; ++i) {
            int lin = tid + i * 256;
            int row = lin >> 2;          // 0..127
            int c4  = lin & 3;           // 0..3  (k group of 4)
            float4 v = *(const float4*)(Xb + (size_t)row * H_ + k0 + c4 * 4);
            As[c4 * 4 + 0][row] = v.x;
            As[c4 * 4 + 1][row] = v.y;
            As[c4 * 4 + 2][row] = v.z;
            As[c4 * 4 + 3][row] = v.w;
        }
        // ---- stage B: 16 k-rows x 64 cols = 256 float4, 1 per thread
        {
            int row = tid >> 4;          // 0..15
            int c4  = tid & 15;          // 0..15
            float4 v = *(const float4*)(Wb + (size_t)(k0 + row) * H_ + c4 * 4);
            *(float4*)(&Bs[row][c4 * 4]) = v;
        }
        __syncthreads();

#pragma unroll
        for (int k = 0; k < BK; ++k) {
            float4 a0 = *(const float4*)&As[k][ty * TM];
            float4 a1 = *(const float4*)&As[k][ty * TM + 4];
            float4 b0 = *(const float4*)&Bs[k][tx * TN];
            float av[TM] = {a0.x, a0.y, a0.z, a0.w, a1.x, a1.y, a1.z, a1.w};
            float bv[TN] = {b0.x, b0.y, b0.z, b0.w};
#pragma unroll
            for (int i = 0; i < TM; ++i)
#pragma unroll
                for (int j = 0; j < TN; ++j)
                    c[i][j] += av[i] * bv[j];
        }
        __syncthreads();
    }

    // ---- epilogue: rows ty*TM+i, cols tx*TN (float4)
#pragma unroll
    for (int i = 0; i < TM; ++i) {
        *(float4*)(Ob + (size_t)(ty * TM + i) * H_ + tx * TN) = *(float4*)&c[i][0];
    }
}

extern "C" void kernel_launch(void* const* d_in, const int* in_sizes, int n_in,
                              void* d_out, int out_size, void* d_ws, size_t ws_size,
                              hipStream_t stream) {
    const float* x     = (const float*)d_in[0];   // [8][4096][256]
    const float* t     = (const float*)d_in[1];   // [8][1]
    const float* osc   = (const float*)d_in[2];   // [6][256][256]
    const float* phase = (const float*)d_in[3];   // [6][256]
    float* W   = (float*)d_ws;                    // 2 MB scratch
    float* out = (float*)d_out;

    build_w<<<2048, 256, 0, stream>>>(osc, t, phase, W);

    dim3 grid(H_ / BN, N_ / BM, B_);              // (4, 32, 8)
    gemm<<<grid, 256, 0, stream>>>(x, W, out);
}

// Round 2
// 109.720 us; speedup vs baseline: 1.2806x; 1.2806x over previous
//
#include <hip/hip_runtime.h>
#include <hip/hip_bf16.h>

// Problem: B=8, N=4096, H=256, F=6
//   W_b[h,k] = sum_f osc[f,h,k] * sin(freq_f * t[b] + phase[f,k])
//   out[b,n,k] = sum_h x[b,n,h] * W_b[h,k]
//
// Kernel 1: build Wt[b][n][h] in bf16 (transposed so GEMM B-fragments are
//           contiguous in k=h) into d_ws  [8][256][256] bf16 = 1 MB
// Kernel 2: per-batch MFMA GEMM, 128x128 tile, BK=32, 4 waves, each wave
//           4x4 tiles of mfma_f32_16x16x32_bf16. X converted fp32->bf16
//           in-register during staging (fuses the cast; no extra pass).

#define B_  8
#define N_  4096
#define H_  256

typedef __attribute__((ext_vector_type(8))) short s8v;   // 8 bf16 = 4 VGPRs (A/B frag)
typedef __attribute__((ext_vector_type(4))) float f4v;   // C/D frag

__global__ __launch_bounds__(256) void build_w(
    const float* __restrict__ osc,     // [6][256][256]  osc[f][h][n]
    const float* __restrict__ t,       // [8][1]
    const float* __restrict__ phase,   // [6][256]       phase[f][n]
    __hip_bfloat16* __restrict__ Wt)   // [8][256][256]  Wt[b][n][h]
{
    const float freqs[6] = {1.f, 2.f, 4.f, 8.f, 7.f, 5.f};
    int idx = blockIdx.x * 256 + threadIdx.x;   // grid = 2048 blocks covers 8*256*256
    int b   = idx >> 16;
    int rem = idx & 65535;
    int n   = rem >> 8;     // output-dim index (phase/res dim)
    int h   = rem & 255;    // GEMM-K index
    float tb  = t[b];
    float acc = 0.f;
#pragma unroll
    for (int f = 0; f < 6; ++f) {
        float s = __sinf(freqs[f] * tb + phase[f * 256 + n]);
        acc += osc[f * 65536 + h * 256 + n] * s;
    }
    Wt[idx] = __float2bfloat16(acc);
}

// LDS tiles padded to stride 40 shorts (80 B): bank = (row*20 + quad*4) % 32
// -> at most 2-way aliasing per 16-lane group, which is free (m136).
#define LDSTRIDE 40

__global__ __launch_bounds__(256) void gemm(
    const float* __restrict__ X,              // [8][4096][256] fp32
    const __hip_bfloat16* __restrict__ Wt,    // [8][256][256]  bf16, [b][n][h]
    float* __restrict__ out)                  // [8][4096][256] fp32
{
    __shared__ short As[128 * LDSTRIDE];      // As[m][k], k contiguous
    __shared__ short Bs[128 * LDSTRIDE];      // Bs[n][k], k contiguous

    const int b     = blockIdx.z;
    const int mTile = blockIdx.y;   // 0..31
    const int nTile = blockIdx.x;   // 0..1

    const int tid    = threadIdx.x;
    const int lane   = tid & 63;
    const int wave   = tid >> 6;    // 0..3
    const int lane15 = lane & 15;
    const int quad   = lane >> 4;   // 0..3
    const int wm     = wave >> 1;   // wave row (2x2 wave grid over 128x128)
    const int wn     = wave & 1;

    const float* Xb          = X   + (size_t)b * N_ * H_ + (size_t)mTile * 128 * H_;
    const __hip_bfloat16* Wb = Wt  + (size_t)b * H_ * H_ + (size_t)nTile * 128 * H_;
    float* Ob                = out + (size_t)b * N_ * H_ + (size_t)mTile * 128 * H_ + nTile * 128;

    // staging assignment: thread -> (row sm, 16-wide k-half sh)
    const int sm = tid >> 1;        // 0..127
    const int sh = tid & 1;         // 0..1

    f4v acc[4][4] = {};             // 64 VGPRs of accumulator

    for (int k0 = 0; k0 < H_; k0 += 32) {
        // ---- stage A: 128 rows x 32 k fp32. Lane pair (2r,2r+1) covers one
        // full 128 B line per row -> no over-fetch. Convert to bf16 in-reg.
        const float4* pa = (const float4*)(Xb + (size_t)sm * H_ + k0 + sh * 16);
        float4 a0 = pa[0], a1 = pa[1], a2 = pa[2], a3 = pa[3];
        union { __hip_bfloat162 h[8]; uint4 q[2]; } cv;
        cv.h[0] = __float22bfloat162_rn(make_float2(a0.x, a0.y));
        cv.h[1] = __float22bfloat162_rn(make_float2(a0.z, a0.w));
        cv.h[2] = __float22bfloat162_rn(make_float2(a1.x, a1.y));
        cv.h[3] = __float22bfloat162_rn(make_float2(a1.z, a1.w));
        cv.h[4] = __float22bfloat162_rn(make_float2(a2.x, a2.y));
        cv.h[5] = __float22bfloat162_rn(make_float2(a2.z, a2.w));
        cv.h[6] = __float22bfloat162_rn(make_float2(a3.x, a3.y));
        cv.h[7] = __float22bfloat162_rn(make_float2(a3.z, a3.w));
        *(uint4*)(&As[sm * LDSTRIDE + sh * 16 + 0]) = cv.q[0];
        *(uint4*)(&As[sm * LDSTRIDE + sh * 16 + 8]) = cv.q[1];

        // ---- stage B: 128 n-rows x 32 k bf16, already transposed in Wt
        const uint4* pb = (const uint4*)(Wb + (size_t)sm * H_ + k0 + sh * 16);
        uint4 b0 = pb[0], b1 = pb[1];
        *(uint4*)(&Bs[sm * LDSTRIDE + sh * 16 + 0]) = b0;
        *(uint4*)(&Bs[sm * LDSTRIDE + sh * 16 + 8]) = b1;
        __syncthreads();

        // ---- fragments: A[m=lane15][k=quad*8+j], B[n=lane15][k=quad*8+j]
        s8v af[4], bf[4];
#pragma unroll
        for (int mt = 0; mt < 4; ++mt)
            af[mt] = *(const s8v*)(&As[(wm * 64 + mt * 16 + lane15) * LDSTRIDE + quad * 8]);
#pragma unroll
        for (int nt = 0; nt < 4; ++nt)
            bf[nt] = *(const s8v*)(&Bs[(wn * 64 + nt * 16 + lane15) * LDSTRIDE + quad * 8]);

#pragma unroll
        for (int mt = 0; mt < 4; ++mt)
#pragma unroll
            for (int nt = 0; nt < 4; ++nt)
                acc[mt][nt] = __builtin_amdgcn_mfma_f32_16x16x32_bf16(
                    af[mt], bf[nt], acc[mt][nt], 0, 0, 0);
        __syncthreads();
    }

    // ---- epilogue: C/D layout col=lane15, row=quad*4+reg (verified m89/m91)
#pragma unroll
    for (int mt = 0; mt < 4; ++mt) {
#pragma unroll
        for (int r = 0; r < 4; ++r) {
            int row = wm * 64 + mt * 16 + quad * 4 + r;
            float* po = Ob + (size_t)row * H_ + wn * 64 + lane15;
#pragma unroll
            for (int nt = 0; nt < 4; ++nt)
                po[nt * 16] = acc[mt][nt][r];
        }
    }
}

extern "C" void kernel_launch(void* const* d_in, const int* in_sizes, int n_in,
                              void* d_out, int out_size, void* d_ws, size_t ws_size,
                              hipStream_t stream) {
    const float* x     = (const float*)d_in[0];   // [8][4096][256]
    const float* t     = (const float*)d_in[1];   // [8][1]
    const float* osc   = (const float*)d_in[2];   // [6][256][256]
    const float* phase = (const float*)d_in[3];   // [6][256]
    __hip_bfloat16* Wt = (__hip_bfloat16*)d_ws;   // 1 MB scratch, rebuilt every call
    float* out = (float*)d_out;

    build_w<<<2048, 256, 0, stream>>>(osc, t, phase, Wt);

    dim3 grid(2, 32, 8);                          // (nTile, mTile, batch) = 512 blocks
    gemm<<<grid, 256, 0, stream>>>(x, Wt, out);
}

// Round 3
// 109.661 us; speedup vs baseline: 1.2813x; 1.0005x over previous
//
#include <hip/hip_runtime.h>
#include <hip/hip_bf16.h>

// Problem: B=8, N=4096, H=256, F=6
//   W_b[h,k] = sum_f osc[f,h,k] * sin(freq_f * t[b] + phase[f,k])
//   out[b,n,k] = sum_h x[b,n,h] * W_b[h,k]
//
// Kernel 1: build Wt[b][n][h] bf16 (transposed: GEMM B-frags contiguous in k=h)
// Kernel 2: per-batch MFMA GEMM, 128x128 tile, BK=32, **512 threads / 8 waves**
//           (wave = 32x64 subtile, 2x4 mfma_f32_16x16x32_bf16), with
//           register-prefetch double buffering: iter k+1's global loads are
//           issued before iter k's MFMA section, hiding HBM latency.
// Grid (mTile, nTile, b): the two nTile blocks sharing X rows differ by 32 in
// linear id (32 % 8 == 0) -> same XCD under round-robin -> L2 hit on 2nd read.

#define B_  8
#define N_  4096
#define H_  256

typedef __attribute__((ext_vector_type(8))) short s8v;   // 8 bf16 (A/B frag)
typedef __attribute__((ext_vector_type(4))) float f4v;   // C/D frag

__global__ __launch_bounds__(256) void build_w(
    const float* __restrict__ osc,     // [6][256][256]  osc[f][h][n]
    const float* __restrict__ t,       // [8][1]
    const float* __restrict__ phase,   // [6][256]       phase[f][n]
    __hip_bfloat16* __restrict__ Wt)   // [8][256][256]  Wt[b][n][h]
{
    const float freqs[6] = {1.f, 2.f, 4.f, 8.f, 7.f, 5.f};
    int idx = blockIdx.x * 256 + threadIdx.x;
    int b   = idx >> 16;
    int rem = idx & 65535;
    int n   = rem >> 8;     // output-dim index (phase dim)
    int h   = rem & 255;    // GEMM-K index
    float tb  = t[b];
    float acc = 0.f;
#pragma unroll
    for (int f = 0; f < 6; ++f) {
        float s = __sinf(freqs[f] * tb + phase[f * 256 + n]);
        acc += osc[f * 65536 + h * 256 + n] * s;
    }
    Wt[idx] = __float2bfloat16(acc);
}

// LDS row stride 40 shorts (80 B): b128 bank group (row*20 + kq*4) % 32
// -> at most 2-way aliasing, which is free (m136).
#define LDSTRIDE 40

__global__ __launch_bounds__(512) void gemm(
    const float* __restrict__ X,              // [8][4096][256] fp32
    const __hip_bfloat16* __restrict__ Wt,    // [8][256][256]  bf16 [b][n][h]
    float* __restrict__ out)                  // [8][4096][256] fp32
{
    __shared__ short As[128 * LDSTRIDE];      // As[m][k]
    __shared__ short Bs[128 * LDSTRIDE];      // Bs[n][k]

    const int b     = blockIdx.z;
    const int mTile = blockIdx.x;   // 0..31
    const int nTile = blockIdx.y;   // 0..1

    const int tid    = threadIdx.x;
    const int lane   = tid & 63;
    const int wave   = tid >> 6;    // 0..7
    const int lane15 = lane & 15;
    const int quad   = lane >> 4;   // 0..3
    const int wm     = wave >> 1;   // 0..3: row band of 32
    const int wn     = wave & 1;    // 0..1: col band of 64

    const float* Xb          = X   + (size_t)b * N_ * H_ + (size_t)mTile * 128 * H_;
    const __hip_bfloat16* Wb = Wt  + (size_t)b * H_ * H_ + (size_t)nTile * 128 * H_;
    float* Ob                = out + (size_t)b * N_ * H_ + (size_t)mTile * 128 * H_ + nTile * 128;

    // staging: thread -> (row, 8-wide k-quarter). 512 thr cover 128 rows x 32 k.
    const int srow = tid >> 2;      // 0..127
    const int skq  = tid & 3;       // 0..3

    const float* pa          = Xb + (size_t)srow * H_ + skq * 8;
    const __hip_bfloat16* pb = Wb + (size_t)srow * H_ + skq * 8;

    f4v acc[2][4] = {};             // 32 VGPRs accumulator

    // ---- prefetch iter 0
    float4 a0 = *(const float4*)(pa);
    float4 a1 = *(const float4*)(pa + 4);
    uint4  bv = *(const uint4*)(pb);

    for (int it = 0; it < 8; ++it) {
        // ---- stage regs -> LDS (convert A fp32->bf16 in-register)
        union { __hip_bfloat162 h[4]; uint4 q; } cv;
        cv.h[0] = __float22bfloat162_rn(make_float2(a0.x, a0.y));
        cv.h[1] = __float22bfloat162_rn(make_float2(a0.z, a0.w));
        cv.h[2] = __float22bfloat162_rn(make_float2(a1.x, a1.y));
        cv.h[3] = __float22bfloat162_rn(make_float2(a1.z, a1.w));
        *(uint4*)(&As[srow * LDSTRIDE + skq * 8]) = cv.q;
        *(uint4*)(&Bs[srow * LDSTRIDE + skq * 8]) = bv;
        __syncthreads();

        // ---- prefetch iter+1 (overlaps with MFMA below)
        if (it < 7) {
            const float4* na          = (const float4*)(pa + (it + 1) * 32);
            a0 = na[0];
            a1 = na[1];
            bv = *(const uint4*)(pb + (it + 1) * 32);
        }

        // ---- fragments: A[m=lane15][k=quad*8+j], B[n=lane15][k=quad*8+j]
        s8v af[2], bf[4];
#pragma unroll
        for (int mt = 0; mt < 2; ++mt)
            af[mt] = *(const s8v*)(&As[(wm * 32 + mt * 16 + lane15) * LDSTRIDE + quad * 8]);
#pragma unroll
        for (int nt = 0; nt < 4; ++nt)
            bf[nt] = *(const s8v*)(&Bs[(wn * 64 + nt * 16 + lane15) * LDSTRIDE + quad * 8]);

#pragma unroll
        for (int mt = 0; mt < 2; ++mt)
#pragma unroll
            for (int nt = 0; nt < 4; ++nt)
                acc[mt][nt] = __builtin_amdgcn_mfma_f32_16x16x32_bf16(
                    af[mt], bf[nt], acc[mt][nt], 0, 0, 0);
        __syncthreads();
    }

    // ---- epilogue: C/D layout col=lane15, row=quad*4+reg (verified m89/m91)
#pragma unroll
    for (int mt = 0; mt < 2; ++mt) {
#pragma unroll
        for (int r = 0; r < 4; ++r) {
            int row = wm * 32 + mt * 16 + quad * 4 + r;
            float* po = Ob + (size_t)row * H_ + wn * 64 + lane15;
#pragma unroll
            for (int nt = 0; nt < 4; ++nt)
                po[nt * 16] = acc[mt][nt][r];
        }
    }
}

extern "C" void kernel_launch(void* const* d_in, const int* in_sizes, int n_in,
                              void* d_out, int out_size, void* d_ws, size_t ws_size,
                              hipStream_t stream) {
    const float* x     = (const float*)d_in[0];   // [8][4096][256]
    const float* t     = (const float*)d_in[1];   // [8][1]
    const float* osc   = (const float*)d_in[2];   // [6][256][256]
    const float* phase = (const float*)d_in[3];   // [6][256]
    __hip_bfloat16* Wt = (__hip_bfloat16*)d_ws;   // 1 MB scratch, rebuilt every call
    float* out = (float*)d_out;

    build_w<<<2048, 256, 0, stream>>>(osc, t, phase, Wt);

    dim3 grid(32, 2, 8);                          // (mTile, nTile, batch) = 512 blocks
    gemm<<<grid, 512, 0, stream>>>(x, Wt, out);
}

// Round 4
// 101.348 us; speedup vs baseline: 1.3864x; 1.0820x over previous
//
#include <hip/hip_runtime.h>
#include <hip/hip_bf16.h>

// Problem: B=8, N=4096, H=256, F=6
//   Wt[b][n][h] = sum_f osc[f][h][n] * sin(freq_f * t[b] + phase[f][n])
//   out[b][m][n] = sum_h x[b][m][h] * Wt[b][n][h]
//
// R4 changes (theory: X nTile-duplication + uncoalesced osc reads were the
// residual ~45us):
//  - gemm: BM=64 x BN=256 tile -> each X row read by exactly ONE block;
//    X HBM traffic = 33.5 MB by construction. Wt[b] (128 KB) is L2-hot.
//  - build_w: lanes on n (coalesced osc), sin hoisted (24/thread), LDS
//    transpose so Wt store is coalesced too.

#define B_  8
#define N_  4096
#define H_  256

typedef __attribute__((ext_vector_type(8))) short s8v;   // 8 bf16 (A/B frag)
typedef __attribute__((ext_vector_type(4))) float f4v;   // C/D frag

__global__ __launch_bounds__(256) void build_w(
    const float* __restrict__ osc,     // [6][256][256]  osc[f][h][n]
    const float* __restrict__ t,       // [8][1]
    const float* __restrict__ phase,   // [6][256]       phase[f][n]
    __hip_bfloat16* __restrict__ Wt)   // [8][256][256]  Wt[b][n][h]
{
    const float freqs[6] = {1.f, 2.f, 4.f, 8.f, 7.f, 5.f};
    __shared__ float tr[16 * 68];      // [hlocal][n], stride 68 (16B-aligned, <=2-way banks)

    const int b  = blockIdx.z;
    const int n0 = blockIdx.y * 64;    // 4 n-tiles
    const int h0 = blockIdx.x * 128;   // 2 h-halves
    const int tid = threadIdx.x;

    const float tb = t[b];
    // read/accum phase: lane -> (h row hr, 4-wide n chunk nr)
    const int nr = (tid & 15) * 4;
    const int hr = tid >> 4;           // 0..15
    // sin precompute: depends on (f, n) only — hoisted out of the h loop
    float s[6][4];
#pragma unroll
    for (int f = 0; f < 6; ++f)
#pragma unroll
        for (int j = 0; j < 4; ++j)
            s[f][j] = __sinf(freqs[f] * tb + phase[f * 256 + n0 + nr + j]);

    // write phase: lane -> (n row nw, 4-wide h chunk hw)
    const int nw = tid >> 2;           // 0..63
    const int hw = (tid & 3) * 4;      // 0,4,8,12
    __hip_bfloat16* wout = Wt + (size_t)b * 65536 + (size_t)(n0 + nw) * 256 + h0;

    for (int hp = 0; hp < 8; ++hp) {
        const int h = h0 + hp * 16 + hr;
        float4 acc = make_float4(0.f, 0.f, 0.f, 0.f);
#pragma unroll
        for (int f = 0; f < 6; ++f) {
            float4 o = *(const float4*)&osc[f * 65536 + h * 256 + n0 + nr];
            acc.x += o.x * s[f][0];
            acc.y += o.y * s[f][1];
            acc.z += o.z * s[f][2];
            acc.w += o.w * s[f][3];
        }
        __syncthreads();                       // previous hp's tr reads done
        *(float4*)&tr[hr * 68 + nr] = acc;
        __syncthreads();
        float v0 = tr[(hw + 0) * 68 + nw];
        float v1 = tr[(hw + 1) * 68 + nw];
        float v2 = tr[(hw + 2) * 68 + nw];
        float v3 = tr[(hw + 3) * 68 + nw];
        union { __hip_bfloat162 h2[2]; unsigned long long q; } cv;
        cv.h2[0] = __float22bfloat162_rn(make_float2(v0, v1));
        cv.h2[1] = __float22bfloat162_rn(make_float2(v2, v3));
        *(unsigned long long*)(wout + hp * 16 + hw) = cv.q;   // coalesced b64
    }
}

// LDS row stride 40 shorts (80 B): 16B-aligned, mild (<=4-way) aliasing only.
#define LDST 40

__global__ __launch_bounds__(512, 4) void gemm(
    const float* __restrict__ X,              // [8][4096][256] fp32
    const __hip_bfloat16* __restrict__ Wt,    // [8][256][256]  bf16 [b][n][h]
    float* __restrict__ out)                  // [8][4096][256] fp32
{
    __shared__ short As[64 * LDST];           // As[m][k]   5.1 KB
    __shared__ short Bs[256 * LDST];          // Bs[n][k]  20.5 KB

    const int b     = blockIdx.y;
    const int mTile = blockIdx.x;             // 0..63, BM=64

    const int tid    = threadIdx.x;
    const int lane   = tid & 63;
    const int wave   = tid >> 6;              // 0..7
    const int lane15 = lane & 15;
    const int quad   = lane >> 4;             // 0..3
    const int wm     = wave >> 2;             // 0..1: 32-row band
    const int wn     = wave & 3;              // 0..3: 64-col band

    const float* Xb          = X   + (size_t)b * N_ * H_ + (size_t)mTile * 64 * H_;
    const __hip_bfloat16* Wb = Wt  + (size_t)b * H_ * H_;
    float* Ob                = out + (size_t)b * N_ * H_ + (size_t)mTile * 64 * H_;

    // A staging: 64 rows x 32 k fp32 = 8 KB. thread -> (row, 4-float seg)
    const int arow = tid >> 3;                // 0..63
    const int aseg = tid & 7;                 // 0..7
    const float* pa = Xb + (size_t)arow * H_ + aseg * 4;

    // B staging: 256 rows x 32 k bf16 = 16 KB. thread -> (row, 16-short half)
    const int brow = tid >> 1;                // 0..255
    const int bh   = tid & 1;                 // 0..1
    const __hip_bfloat16* pb = Wb + (size_t)brow * H_ + bh * 16;

    f4v acc[2][4] = {};

    // prefetch iter 0
    float4 av = *(const float4*)pa;
    uint4  bv0 = *(const uint4*)(pb);
    uint4  bv1 = *(const uint4*)(pb + 8);

    for (int it = 0; it < 8; ++it) {
        // stage regs -> LDS (A converted fp32->bf16 in-register)
        union { __hip_bfloat162 h2[2]; unsigned long long q; } cv;
        cv.h2[0] = __float22bfloat162_rn(make_float2(av.x, av.y));
        cv.h2[1] = __float22bfloat162_rn(make_float2(av.z, av.w));
        *(unsigned long long*)(&As[arow * LDST + aseg * 4]) = cv.q;
        *(uint4*)(&Bs[brow * LDST + bh * 16 + 0]) = bv0;
        *(uint4*)(&Bs[brow * LDST + bh * 16 + 8]) = bv1;
        __syncthreads();

        // prefetch iter+1 (overlaps the MFMA section)
        if (it < 7) {
            av  = *(const float4*)(pa + (it + 1) * 32);
            bv0 = *(const uint4*)(pb + (it + 1) * 32);
            bv1 = *(const uint4*)(pb + (it + 1) * 32 + 8);
        }

        // fragments: A[m=lane15][k=quad*8+j], B[n=lane15][k=quad*8+j]
        s8v af[2], bf[4];
#pragma unroll
        for (int mt = 0; mt < 2; ++mt)
            af[mt] = *(const s8v*)(&As[(wm * 32 + mt * 16 + lane15) * LDST + quad * 8]);
#pragma unroll
        for (int nt = 0; nt < 4; ++nt)
            bf[nt] = *(const s8v*)(&Bs[(wn * 64 + nt * 16 + lane15) * LDST + quad * 8]);

#pragma unroll
        for (int mt = 0; mt < 2; ++mt)
#pragma unroll
            for (int nt = 0; nt < 4; ++nt)
                acc[mt][nt] = __builtin_amdgcn_mfma_f32_16x16x32_bf16(
                    af[mt], bf[nt], acc[mt][nt], 0, 0, 0);
        __syncthreads();
    }

    // epilogue: C/D layout col=lane15, row=quad*4+reg (verified m89/m91)
#pragma unroll
    for (int mt = 0; mt < 2; ++mt) {
#pragma unroll
        for (int r = 0; r < 4; ++r) {
            int row = wm * 32 + mt * 16 + quad * 4 + r;
            float* po = Ob + (size_t)row * H_ + wn * 64 + lane15;
#pragma unroll
            for (int nt = 0; nt < 4; ++nt)
                po[nt * 16] = acc[mt][nt][r];
        }
    }
}

extern "C" void kernel_launch(void* const* d_in, const int* in_sizes, int n_in,
                              void* d_out, int out_size, void* d_ws, size_t ws_size,
                              hipStream_t stream) {
    const float* x     = (const float*)d_in[0];   // [8][4096][256]
    const float* t     = (const float*)d_in[1];   // [8][1]
    const float* osc   = (const float*)d_in[2];   // [6][256][256]
    const float* phase = (const float*)d_in[3];   // [6][256]
    __hip_bfloat16* Wt = (__hip_bfloat16*)d_ws;   // 1 MB scratch, rebuilt every call
    float* out = (float*)d_out;

    dim3 gw(2, 4, 8);                             // (h-half, n-tile, b) = 64 blocks
    build_w<<<gw, 256, 0, stream>>>(osc, t, phase, Wt);

    dim3 gg(64, 8);                               // (mTile, b) = 512 blocks
    gemm<<<gg, 512, 0, stream>>>(x, Wt, out);
}